// Round 9
// baseline (2046.131 us; speedup 1.0000x reference)
//
#include <hip/hip_runtime.h>
#include <math.h>

// QLSTMHarmonic: persistent LSTM, 256 blk x 256 thr x NBATCH=2 elems/thread.
// r9 = r8 numerics (bit-exact, absmax 0.0 r3-r8) with two isolated levers:
//  1) NBATCH=2: each ds_read_b128 weight load feeds BOTH elements' packed
//     fmas -> DS instr/CU/step halves (r8 analysis: DS ~645us was the
//     compute-segment limiter, not VALU).
//  2) barrier publish via atomic_exchange (executes at LLC -> prompt
//     cross-XCD visibility) instead of relaxed store.
// Geometry: 4 waves/block, 1 block/CU, launch_bounds(256,1) -> VGPR<=512.
// Per-element instruction sequence identical to r8 -> bit-exact unchanged.

#define NBLK  256
#define NTHR  256
#define NB    2      // batch elems per thread
#define SEQL  64
#define HIDN  20
#define G4    80     // 4*HID gates

typedef float f2 __attribute__((ext_vector_type(2)));
typedef unsigned long long u64;

// XLA/Eigen f32 tanh rational approximation (bit-exact vs reference, r3-r8).
__device__ __forceinline__ float tanh_xla(float x){
  const float kClamp = 7.90531110763549805f;
  float xc = fminf(fmaxf(x, -kClamp), kClamp);
  float x2 = xc*xc;
  float p = fmaf(x2, -2.76076847742355e-16f, 2.00018790482477e-13f);
  p = fmaf(x2, p, -8.60467152213735e-11f);
  p = fmaf(x2, p,  5.12229709037114e-08f);
  p = fmaf(x2, p,  1.48572235717979e-05f);
  p = fmaf(x2, p,  6.37261928875436e-04f);
  p = fmaf(x2, p,  4.89352455891786e-03f);
  p = p * xc;
  float q = fmaf(x2, 1.19825839466702e-06f, 1.18534705686654e-04f);
  q = fmaf(x2, q, 2.26843463243900e-03f);
  q = fmaf(x2, q, 4.89352518554385e-03f);
  float y = p / q;                       // IEEE div, as XLA emits
  return (fabsf(x) < 4e-4f) ? x : y;     // XLA small-x passthrough
}

// n = rintf(RN(x/s)) without a division in the common case (bit-exact r4-r8).
__device__ __forceinline__ float qround(float x, float s, float inv_s, float tol){
  float n = rintf(__fmul_rn(x, inv_s));
  float e = fmaf(-n, s, x);
  if (__builtin_expect(fabsf(fabsf(e) - 0.5f*s) <= tol*s, 0))
    n = rintf(x / s);
  return n;
}

// Combined global max-reduce + barrier, zero __syncthreads (validated r8).
// In-block: tagged LDS words. Cross-block: relaxed u64 {tag,val} slots,
// 2 rows, row=phase&1, tag=phase+1. Publish via atomic_exchange (r9 lever:
// executes at LLC for prompt cross-XCD visibility). 4 waves/block.
__device__ __forceinline__ float phase_max(float lmax, int phase,
                                           u64* slots, int blk, int tid,
                                           volatile u64* s_red64,
                                           volatile u64* s_bc64)
{
  #pragma unroll
  for (int off=32; off; off>>=1) lmax = fmaxf(lmax, __shfl_xor(lmax, off, 64));
  const int wid = tid>>6, lane = tid&63;
  const unsigned int tag = (unsigned int)(phase+1);
  const u64 tw = ((u64)tag)<<32;
  if (lane==0) s_red64[wid] = tw | (u64)__float_as_uint(lmax);
  if (wid==0) {
    // gather the 4 per-wave partials by tag-spin (lanes 0..3)
    u64 pv = 0;
    if (lane<4) { do { pv = s_red64[lane]; } while ((unsigned int)(pv>>32)!=tag); }
    float bm = (lane<4) ? __uint_as_float((unsigned int)pv) : 0.f;
    bm = fmaxf(bm, __shfl_xor(bm,2,64));
    bm = fmaxf(bm, __shfl_xor(bm,1,64));
    u64* sp = slots + (size_t)(phase&1)*NBLK;
    if (lane==0)
      (void)__hip_atomic_exchange(sp+blk, tw | (u64)__float_as_uint(bm),
                                  __ATOMIC_RELAXED, __HIP_MEMORY_SCOPE_AGENT);
    u64 v0,v1,v2,v3;
    for (;;) {
      v0 = __hip_atomic_load(sp+lane,     __ATOMIC_RELAXED, __HIP_MEMORY_SCOPE_AGENT);
      v1 = __hip_atomic_load(sp+lane+64,  __ATOMIC_RELAXED, __HIP_MEMORY_SCOPE_AGENT);
      v2 = __hip_atomic_load(sp+lane+128, __ATOMIC_RELAXED, __HIP_MEMORY_SCOPE_AGENT);
      v3 = __hip_atomic_load(sp+lane+192, __ATOMIC_RELAXED, __HIP_MEMORY_SCOPE_AGENT);
      bool ok = ((unsigned int)(v0>>32)==tag) && ((unsigned int)(v1>>32)==tag) &&
                ((unsigned int)(v2>>32)==tag) && ((unsigned int)(v3>>32)==tag);
      if (__all(ok)) break;
      __builtin_amdgcn_s_sleep(1);
    }
    unsigned int m0 = (unsigned int)v0, m1 = (unsigned int)v1;
    unsigned int m2 = (unsigned int)v2, m3 = (unsigned int)v3;
    unsigned int m = m0>m1?m0:m1; if (m2>m) m=m2; if (m3>m) m=m3;
    #pragma unroll
    for (int off=32; off; off>>=1) {
      unsigned int o = (unsigned int)__shfl_xor((int)m, off, 64);
      if (o>m) m=o;
    }
    if (lane==0) *s_bc64 = tw | (u64)m;      // non-neg floats: uint cmp == float cmp
  }
  u64 bv;
  do { bv = *s_bc64; } while ((unsigned int)(bv>>32)!=tag);
  return __uint_as_float((unsigned int)bv);
}

__global__ void kinit(float* __restrict__ ws) {
  int i = threadIdx.x;
  for (; i < 1152; i += 256) ws[i] = 0.0f;     // xmax + scales + 2x256 u64 slots
}

__global__ void kmaxabs_x(const float4* __restrict__ x4, int n4, int* __restrict__ xmax_bits) {
  float m = 0.f;
  int stride = gridDim.x*blockDim.x;
  for (int i = blockIdx.x*blockDim.x + threadIdx.x; i < n4; i += stride) {
    float4 v = x4[i];
    m = fmaxf(fmaxf(fabsf(v.x),fabsf(v.y)), fmaxf(fmaxf(fabsf(v.z),fabsf(v.w)), m));
  }
  #pragma unroll
  for (int off=32; off; off>>=1) m = fmaxf(m, __shfl_xor(m, off, 64));
  __shared__ float red[4];
  int wid = threadIdx.x>>6, lane = threadIdx.x&63;
  if (lane==0) red[wid]=m;
  __syncthreads();
  if (threadIdx.x==0) {
    float bm = fmaxf(fmaxf(red[0],red[1]), fmaxf(red[2],red[3]));
    atomicMax(xmax_bits, __float_as_int(bm));  // ws[0] zeroed by kinit; values >= 0
  }
}

__global__ void kscales(const float* __restrict__ wih, const float* __restrict__ whh,
                        const float* __restrict__ W1, const float* __restrict__ W2,
                        const float* __restrict__ W3, float* __restrict__ ws)
{
  int wid = threadIdx.x>>6, lane = threadIdx.x&63;
  const float* p; int n;
  if      (wid==0){p=wih;n=80;}   else if (wid==1){p=whh;n=1600;}
  else if (wid==2){p=W1;n=1280;}  else if (wid==3){p=W2;n=2048;}
  else            {p=W3;n=128;}
  float m=0.f;
  for (int i=lane;i<n;i+=64) m=fmaxf(m,fabsf(p[i]));
  #pragma unroll
  for (int off=32; off; off>>=1) m=fmaxf(m,__shfl_xor(m,off,64));
  if (lane==0) ws[9+wid]=fmaxf(m,1e-8f)/127.0f;
  if (threadIdx.x==0) {
    float xm = __int_as_float(((const int*)ws)[0]);
    ws[8]=fmaxf(xm,1e-8f)/127.0f;
  }
}

__global__ void __launch_bounds__(NTHR, 1)
kmain(const float* __restrict__ x, const float* __restrict__ w_ih,
      const float* __restrict__ w_hh, const float* __restrict__ bias,
      const float* __restrict__ W1, const float* __restrict__ b1,
      const float* __restrict__ W2, const float* __restrict__ b2,
      const float* __restrict__ W3, const float* __restrict__ b3,
      float* __restrict__ out, float* __restrict__ ws)
{
  __shared__ float s_whh[HIDN*G4];   // [k][j]
  __shared__ float s_wih[G4];
  __shared__ float s_b[G4];
  __shared__ float s_W1[HIDN*64];    // [k][j]
  __shared__ float s_b1v[64];
  __shared__ float s_W2[64*32];      // [k][j]
  __shared__ float s_b2v[32];
  __shared__ float s_W3[32*4];       // [k][j]
  __shared__ float s_b3v[4];
  __shared__ float s_lutsig[63];     // per-gate-phase: quantized sigmoid of n*s1
  __shared__ float s_luttg[63];      // per-gate-phase: quantized tanh of n*s1
  __shared__ float s_luttc[63];      // per-cell-phase: quantized tanh of m*s2
  __shared__ u64 s_red64[4];
  __shared__ u64 s_bc64;

  const int tid = threadIdx.x;
  const int blk = blockIdx.x;
  u64* slots = (u64*)(ws + 64);      // 2*NBLK u64

  const float sx   = ws[8];
  const float swih = ws[9];
  const float swhh = ws[10];
  const float sw1  = ws[11];
  const float sw2  = ws[12];
  const float sw3  = ws[13];

  // stage + fake-quantize weights into LDS ([k][j] layout, float4 j-reads).
  for (int i = tid; i < G4; i += NTHR) {
    s_wih[i] = fminf(fmaxf(rintf(w_ih[i]/swih), -127.f), 127.f)*swih;
    s_b[i]   = bias[i];
  }
  for (int i = tid; i < HIDN*G4; i += NTHR) {
    int j = i/HIDN, k = i - j*HIDN;           // src w_hh[j][k]
    s_whh[k*G4+j] = fminf(fmaxf(rintf(w_hh[i]/swhh), -127.f), 127.f)*swhh;
  }
  for (int i = tid; i < 64*HIDN; i += NTHR) {
    int j = i/HIDN, k = i - j*HIDN;           // src W1[j][k]
    s_W1[k*64+j] = fminf(fmaxf(rintf(W1[i]/sw1), -127.f), 127.f)*sw1;
  }
  for (int i = tid; i < 32*64; i += NTHR) {
    int j = i>>6, k = i&63;                   // src W2[j][k]
    s_W2[k*32+j] = fminf(fmaxf(rintf(W2[i]/sw2), -127.f), 127.f)*sw2;
  }
  for (int i = tid; i < 4*32; i += NTHR) {
    int j = i>>5, k = i&31;                   // src W3[j][k]
    s_W3[k*4+j] = fminf(fmaxf(rintf(W3[i]/sw3), -127.f), 127.f)*sw3;
  }
  if (tid < 64) s_b1v[tid] = b1[tid];
  if (tid < 32) s_b2v[tid] = b2[tid];
  if (tid < 4)  s_b3v[tid] = b3[tid];
  __syncthreads();

  // two batch elements per thread, 256 apart (keeps x/out patterns of r8)
  const long e0 = (long)blk*(NTHR*NB) + tid;
  const long e1 = e0 + NTHR;
  const float* xr0 = x + e0*SEQL;
  const float* xr1 = x + e1*SEQL;
  const float inv_sx = __builtin_amdgcn_rcpf(sx);

  float h[NB][HIDN], c[NB][HIDN];
  #pragma unroll
  for (int e=0;e<NB;++e)
    #pragma unroll
    for (int k=0;k<HIDN;++k){ h[e][k]=0.f; c[e][k]=0.f; }

  float4 xv0, xv1;
  #pragma unroll 1
  for (int t=0; t<SEQL; ++t) {
    if ((t&3)==0) { xv0 = *(const float4*)(xr0 + t); xv1 = *(const float4*)(xr1 + t); }
    float xa = (t&3)==1 ? xv0.y : ((t&3)==2 ? xv0.z : ((t&3)==3 ? xv0.w : xv0.x));
    float xb = (t&3)==1 ? xv1.y : ((t&3)==2 ? xv1.z : ((t&3)==3 ? xv1.w : xv1.x));
    float xq[NB];
    xq[0] = __fmul_rn(fminf(fmaxf(qround(xa, sx, inv_sx, 1e-4f), -127.f), 127.f), sx);
    xq[1] = __fmul_rn(fminf(fmaxf(qround(xb, sx, inv_sx, 1e-4f), -127.f), 127.f), sx);

    // hw = h @ w_hh^T for both elems; one weight load feeds both packed fmas.
    // Per-elem k-order accumulation identical to r8 -> bit-exact.
    f2 hw2[NB][40];
    #pragma unroll
    for (int e=0;e<NB;++e)
      #pragma unroll
      for (int j=0;j<40;++j) { hw2[e][j].x = 0.f; hw2[e][j].y = 0.f; }
    #pragma unroll
    for (int k=0;k<HIDN;++k) {
      f2 hk2[NB];
      #pragma unroll
      for (int e=0;e<NB;++e) { hk2[e].x = h[e][k]; hk2[e].y = h[e][k]; }
      const float4* w4 = (const float4*)&s_whh[k*G4];
      #pragma unroll
      for (int j4=0;j4<20;++j4) {
        float4 w = w4[j4];
        f2 wlo; wlo.x = w.x; wlo.y = w.y;
        f2 whi; whi.x = w.z; whi.y = w.w;
        #pragma unroll
        for (int e=0;e<NB;++e) {
          hw2[e][2*j4]   = __builtin_elementwise_fma(hk2[e], wlo, hw2[e][2*j4]);
          hw2[e][2*j4+1] = __builtin_elementwise_fma(hk2[e], whi, hw2[e][2*j4+1]);
        }
      }
    }
    // gates = (x@wihT + hw) + b, left-assoc, no contraction (scalar _rn ops)
    float lm = 0.f;
    #pragma unroll
    for (int j4=0;j4<20;++j4) {
      float4 wi = *(const float4*)&s_wih[j4*4];
      float4 bb = *(const float4*)&s_b[j4*4];
      #pragma unroll
      for (int e=0;e<NB;++e) {
        float* hw = (float*)hw2[e];
        float g0 = __fadd_rn(__fadd_rn(__fmul_rn(xq[e], wi.x), hw[j4*4  ]), bb.x);
        float g1 = __fadd_rn(__fadd_rn(__fmul_rn(xq[e], wi.y), hw[j4*4+1]), bb.y);
        float g2 = __fadd_rn(__fadd_rn(__fmul_rn(xq[e], wi.z), hw[j4*4+2]), bb.z);
        float g3 = __fadd_rn(__fadd_rn(__fmul_rn(xq[e], wi.w), hw[j4*4+3]), bb.w);
        hw[j4*4  ]=g0; hw[j4*4+1]=g1; hw[j4*4+2]=g2; hw[j4*4+3]=g3;
        lm = fmaxf(lm, fmaxf(fmaxf(fabsf(g0),fabsf(g1)), fmaxf(fabsf(g2),fabsf(g3))));
      }
    }
    float gm = phase_max(lm, 2*t, slots, blk, tid, s_red64, &s_bc64);
    float s1 = fmaxf(gm, 1e-8f)/31.0f;        // gate_acc scale (uniform)
    float inv1 = __builtin_amdgcn_rcpf(s1);

    // Activation LUTs for the 63 possible quantized-gate values (bit-exact).
    if (tid < 63) {
      float q  = __fmul_rn((float)(tid-31), s1);
      float ti = tanh_xla(0.5f*q);
      int ni = (int)rintf(fmaf(0.5f, ti, 0.5f)*63.0f);
      ni = min(max(ni,0),63);
      s_lutsig[tid] = (float)ni/63.0f;
    } else if (tid >= 64 && tid < 127) {
      int n = tid - 64 - 31;
      float q  = __fmul_rn((float)n, s1);
      float tg = tanh_xla(q);
      int ng = (int)rintf(tg*31.0f);
      ng = min(max(ng,-31),31);
      s_luttg[tid-64] = (float)ng/31.0f;
    }
    __syncthreads();

    float og[NB][HIDN];
    float lm2 = 0.f;
    #pragma unroll
    for (int e=0;e<NB;++e) {
      float* hw = (float*)hw2[e];
      #pragma unroll
      for (int k=0;k<HIDN;++k) {
        int ii = min(max((int)qround(hw[k   ], s1, inv1, 2e-5f),-31),31)+31;
        int fi = min(max((int)qround(hw[20+k], s1, inv1, 2e-5f),-31),31)+31;
        int gi = min(max((int)qround(hw[40+k], s1, inv1, 2e-5f),-31),31)+31;
        int oi = min(max((int)qround(hw[60+k], s1, inv1, 2e-5f),-31),31)+31;
        float iv = s_lutsig[ii];
        float fv = s_lutsig[fi];
        float gv = s_luttg[gi];
        og[e][k] = s_lutsig[oi];
        // c_new = (f*c) + (i*g), unfused
        float pc = __fadd_rn(__fmul_rn(fv, c[e][k]), __fmul_rn(iv, gv));
        c[e][k] = pc;
        lm2 = fmaxf(lm2, fabsf(pc));
      }
    }
    float gm2 = phase_max(lm2, 2*t+1, slots, blk, tid, s_red64, &s_bc64);
    float s2 = fmaxf(gm2, 1e-8f)/31.0f;       // cell_state scale (uniform)
    float inv2 = __builtin_amdgcn_rcpf(s2);
    if (tid < 63) {
      float q  = __fmul_rn((float)(tid-31), s2);
      float tc = tanh_xla(q);
      int nc = (int)rintf(tc*31.0f);
      nc = min(max(nc,-31),31);
      s_luttc[tid] = (float)nc/31.0f;
    }
    __syncthreads();
    #pragma unroll
    for (int e=0;e<NB;++e)
      #pragma unroll
      for (int k=0;k<HIDN;++k) {
        int m = min(max((int)qround(c[e][k], s2, inv2, 2e-5f),-31),31);
        float cn = __fmul_rn((float)m, s2);
        c[e][k] = cn;
        h[e][k] = __fmul_rn(og[e][k], s_luttc[m+31]);
      }
  }

  // ---- MLP head (both elems; LDS float4 weights shared) ----
  float lm3 = 0.f;
  float a0[NB][HIDN];
  #pragma unroll
  for (int e=0;e<NB;++e)
    #pragma unroll
    for (int k=0;k<HIDN;++k){ float r = fmaxf(h[e][k],0.f); a0[e][k]=r; lm3=fmaxf(lm3,r); }
  float gm3 = phase_max(lm3, 128, slots, blk, tid, s_red64, &s_bc64);
  float s3 = fmaxf(gm3,1e-8f)/63.0f;          // unsigned 6b
  float inv3 = __builtin_amdgcn_rcpf(s3);
  #pragma unroll
  for (int e=0;e<NB;++e)
    #pragma unroll
    for (int k=0;k<HIDN;++k)
      a0[e][k] = __fmul_rn(fminf(fmaxf(qround(a0[e][k], s3, inv3, 4e-5f),0.f),63.f), s3);

  float o1[NB][64];
  #pragma unroll
  for (int e=0;e<NB;++e)
    #pragma unroll
    for (int j=0;j<64;++j) o1[e][j] = 0.f;
  #pragma unroll
  for (int k=0;k<HIDN;++k) {
    #pragma unroll
    for (int j=0;j<64;j+=4) {
      float4 w = *(const float4*)&s_W1[k*64+j];
      #pragma unroll
      for (int e=0;e<NB;++e) {
        float ak = a0[e][k];
        o1[e][j]   = fmaf(ak,w.x,o1[e][j]);
        o1[e][j+1] = fmaf(ak,w.y,o1[e][j+1]);
        o1[e][j+2] = fmaf(ak,w.z,o1[e][j+2]);
        o1[e][j+3] = fmaf(ak,w.w,o1[e][j+3]);
      }
    }
  }
  float lm4 = 0.f;
  #pragma unroll
  for (int e=0;e<NB;++e)
    #pragma unroll
    for (int j=0;j<64;++j){ o1[e][j]=fmaxf(__fadd_rn(o1[e][j],s_b1v[j]),0.f); lm4=fmaxf(lm4,o1[e][j]); }
  float gm4 = phase_max(lm4, 129, slots, blk, tid, s_red64, &s_bc64);
  float s4 = fmaxf(gm4,1e-8f)/63.0f;
  float inv4 = __builtin_amdgcn_rcpf(s4);
  #pragma unroll
  for (int e=0;e<NB;++e)
    #pragma unroll
    for (int j=0;j<64;++j)
      o1[e][j] = __fmul_rn(fminf(fmaxf(qround(o1[e][j], s4, inv4, 4e-5f),0.f),63.f), s4);

  float o2[NB][32];
  #pragma unroll
  for (int e=0;e<NB;++e)
    #pragma unroll
    for (int j=0;j<32;++j) o2[e][j] = 0.f;
  #pragma unroll
  for (int k=0;k<64;++k) {
    #pragma unroll
    for (int j=0;j<32;j+=4) {
      float4 w = *(const float4*)&s_W2[k*32+j];
      #pragma unroll
      for (int e=0;e<NB;++e) {
        float ak = o1[e][k];
        o2[e][j]   = fmaf(ak,w.x,o2[e][j]);
        o2[e][j+1] = fmaf(ak,w.y,o2[e][j+1]);
        o2[e][j+2] = fmaf(ak,w.z,o2[e][j+2]);
        o2[e][j+3] = fmaf(ak,w.w,o2[e][j+3]);
      }
    }
  }
  float lm5=0.f;
  #pragma unroll
  for (int e=0;e<NB;++e)
    #pragma unroll
    for (int j=0;j<32;++j){ o2[e][j]=fmaxf(__fadd_rn(o2[e][j],s_b2v[j]),0.f); lm5=fmaxf(lm5,o2[e][j]); }
  float gm5 = phase_max(lm5, 130, slots, blk, tid, s_red64, &s_bc64);
  float s5 = fmaxf(gm5,1e-8f)/63.0f;
  float inv5 = __builtin_amdgcn_rcpf(s5);
  #pragma unroll
  for (int e=0;e<NB;++e)
    #pragma unroll
    for (int j=0;j<32;++j)
      o2[e][j] = __fmul_rn(fminf(fmaxf(qround(o2[e][j], s5, inv5, 4e-5f),0.f),63.f), s5);

  float o3[NB][4];
  #pragma unroll
  for (int e=0;e<NB;++e) { o3[e][0]=0.f; o3[e][1]=0.f; o3[e][2]=0.f; o3[e][3]=0.f; }
  #pragma unroll
  for (int k=0;k<32;++k) {
    float4 w = *(const float4*)&s_W3[k*4];
    #pragma unroll
    for (int e=0;e<NB;++e) {
      float ak = o2[e][k];
      o3[e][0]=fmaf(ak,w.x,o3[e][0]); o3[e][1]=fmaf(ak,w.y,o3[e][1]);
      o3[e][2]=fmaf(ak,w.z,o3[e][2]); o3[e][3]=fmaf(ak,w.w,o3[e][3]);
    }
  }
  float4 r0, r1;
  r0.x = fmaxf(__fadd_rn(o3[0][0],s_b3v[0]),0.f);
  r0.y = fmaxf(__fadd_rn(o3[0][1],s_b3v[1]),0.f);
  r0.z = fmaxf(__fadd_rn(o3[0][2],s_b3v[2]),0.f);
  r0.w = fmaxf(__fadd_rn(o3[0][3],s_b3v[3]),0.f);
  r1.x = fmaxf(__fadd_rn(o3[1][0],s_b3v[0]),0.f);
  r1.y = fmaxf(__fadd_rn(o3[1][1],s_b3v[1]),0.f);
  r1.z = fmaxf(__fadd_rn(o3[1][2],s_b3v[2]),0.f);
  r1.w = fmaxf(__fadd_rn(o3[1][3],s_b3v[3]),0.f);
  ((float4*)out)[e0] = r0;
  ((float4*)out)[e1] = r1;
}

extern "C" void kernel_launch(void* const* d_in, const int* in_sizes, int n_in,
                              void* d_out, int out_size, void* d_ws, size_t ws_size,
                              hipStream_t stream) {
  const float* x    = (const float*)d_in[0];
  const float* w_ih = (const float*)d_in[1];
  const float* w_hh = (const float*)d_in[2];
  const float* b    = (const float*)d_in[3];
  const float* W1   = (const float*)d_in[4];
  const float* b1   = (const float*)d_in[5];
  const float* W2   = (const float*)d_in[6];
  const float* b2   = (const float*)d_in[7];
  const float* W3   = (const float*)d_in[8];
  const float* b3   = (const float*)d_in[9];
  float* out = (float*)d_out;
  float* ws  = (float*)d_ws;

  int n4 = in_sizes[0]/4;
  kinit<<<1,256,0,stream>>>(ws);
  kmaxabs_x<<<1024,256,0,stream>>>((const float4*)x, n4, (int*)ws);
  kscales<<<1,320,0,stream>>>(w_ih,w_hh,W1,W2,W3,ws);
  // Plain launch (NOT cooperative: not graph-capturable). Co-residency:
  // 256 blocks, 1 block/CU x 256 CUs; launch_bounds(256,1) -> VGPR<=512.
  kmain<<<dim3(NBLK), dim3(NTHR), 0, stream>>>(x,w_ih,w_hh,b,W1,b1,W2,b2,W3,b3,out,ws);
}